// Round 1
// 68.117 us; speedup vs baseline: 1.1642x; 1.1642x over previous
//
#include <hip/hip_runtime.h>

// ---------------------------------------------------------------------------
// UpThreeOffsetsConvShareWeights v2: transposed-MFMA + in-register relayout.
//
// Same algebra as before (separable deform offsets -> per-phase 2x2x2-tap
// conv == GEMM M=spatial, N=96, K=512; fused K=96 combine GEMM), but:
//  * Both GEMMs computed as C^T via mfma(W_frag, x_frag): lane = spatial col.
//    A/B fragment layouts are lane-symmetric for 32x32x16, and W_sw / W2_sw
//    already match the A-role layout -> no weight relayout needed.
//  * act relayout for combine GEMM done in-register: v_cvt_pk_bf16_f32 pairs
//    + v_permlane32_swap_b32 (exchanges reg quadrants between lane and
//    lane+32, which hold the same spatial col). Removes actT LDS entirely.
//  * Grid 1024: block = 1 spatial tile (4z x 4y x 8x input) x one (bph,cp)
//    phase pair; waves = (a-phase, y-slab). Block-uniform bph/cp shrinks the
//    halo: xt = [6][5][9][64] = 34.5 KB -> 3+ blocks/CU by LDS.
//  * launch_bounds(256,3): target 3 waves/SIMD (<=170 regs).
//  * Stores: lane = spatial -> 8 lines/instruction instead of 32.
//  * All prep work merged into one kernel (saves 2 launch gaps).
// ---------------------------------------------------------------------------

typedef __bf16 bf16x8 __attribute__((ext_vector_type(8)));
typedef float f32x16 __attribute__((ext_vector_type(16)));
typedef unsigned u32x2 __attribute__((ext_vector_type(2)));

__device__ inline unsigned short f2bf(float f) {
  unsigned int u = __float_as_uint(f);
  u += 0x7FFFu + ((u >> 16) & 1u);
  return (unsigned short)(u >> 16);
}

__device__ inline bf16x8 bc16(uint4 v) { return __builtin_bit_cast(bf16x8, v); }

__device__ inline unsigned cvtpk(float lo, float hi) {
  unsigned r;
  asm("v_cvt_pk_bf16_f32 %0, %1, %2" : "=v"(r) : "v"(lo), "v"(hi));
  return r;
}

// v_permlane32_swap_b32: a[32:63] <-> b[0:31].
// After: lane<32: a=own a, b=partner(lane+32)'s a; lane>=32: a=partner's b, b=own b.
__device__ inline void plswap(unsigned& a, unsigned& b) {
  u32x2 r = __builtin_amdgcn_permlane32_swap(a, b, false, false);
  a = r.x;
  b = r.y;
}

__device__ inline float ucoef(int abit, int k, int jbit, float alpha) {
  if (abit == 0) return (k == 0) ? (jbit ? alpha : 1.f - alpha) : (jbit ? 1.f : 0.f);
  return (k == 2) ? (jbit ? 1.f - alpha : alpha) : (jbit ? 0.f : 1.f);
}

// ---------------- K0: all preprocessing in one kernel (2049 blocks) ---------
//  bid <  512 : transpose x [64][32768] f32 -> xT [32768][64] bf16
//  bid < 2048 : build phase-collapsed, BN1-folded, MFMA-swizzled W_sw
//  bid == 2048: combine-weight fragments + folded biases
__global__ void k_prep(const float* __restrict__ x, unsigned short* __restrict__ xT,
                       const float* __restrict__ w_def, const float* __restrict__ bn1_g,
                       const float* __restrict__ bn1_v, unsigned short* __restrict__ W_sw,
                       const float* __restrict__ w_comb, const float* __restrict__ b_comb,
                       const float* __restrict__ bn2_g, const float* __restrict__ bn2_b,
                       const float* __restrict__ bn2_m, const float* __restrict__ bn2_v,
                       const float* __restrict__ b_def, const float* __restrict__ bn1_b,
                       const float* __restrict__ bn1_m, unsigned short* __restrict__ W2_sw,
                       float* __restrict__ bias1, float* __restrict__ bias2) {
  __shared__ unsigned short t[64][65];
  int bid = blockIdx.x;
  if (bid < 512) {
    int s0 = bid * 64;
    int lane = threadIdx.x & 63;
    int grp = threadIdx.x >> 6;
#pragma unroll
    for (int c = grp; c < 64; c += 4)
      t[c][lane] = f2bf(x[c * 32768 + s0 + lane]);
    __syncthreads();
#pragma unroll
    for (int s = grp; s < 64; s += 4)
      xT[(size_t)(s0 + s) * 64 + lane] = t[lane][s];
  } else if (bid < 2048) {
    int e = (bid - 512) * 256 + threadIdx.x;  // < 393216
    int j = e & 7;
    int lane = (e >> 3) & 63;
    int idx = e >> 9;
    int nt = idx % 3;
    idx /= 3;
    int s = idx & 31;
    int p = idx >> 5;
    int o = lane & 31;
    int br = nt;
    int kk = 16 * s + ((lane >> 5) << 3) + j;
    int tap = kk >> 6, ch = kk & 63;
    int jz = (tap >> 2) & 1, jy = (tap >> 1) & 1, jx = tap & 1;
    int a = (p >> 2) & 1, b = (p >> 1) & 1, cp = p & 1;
    float alpha = (br == 0) ? 0.f : ((br == 1) ? 0.4f : 0.7f);
    const float* wb = w_def + (o * 64 + ch) * 27;
    float sum = 0.f;
    for (int kz = 0; kz < 3; ++kz) {
      float uz = ucoef(a, kz, jz, alpha);
      if (uz == 0.f) continue;
      for (int ky = 0; ky < 3; ++ky) {
        float uy = ucoef(b, ky, jy, alpha);
        if (uy == 0.f) continue;
        float uzy = uz * uy;
        for (int kx = 0; kx < 3; ++kx) {
          float ux = ucoef(cp, kx, jx, alpha);
          if (ux != 0.f) sum += wb[kz * 9 + ky * 3 + kx] * uzy * ux;
        }
      }
    }
    float s1 = bn1_g[o] * rsqrtf(bn1_v[o] + 1e-5f);
    W_sw[e] = f2bf(sum * s1);
  } else {
    int tid = threadIdx.x;
    for (int e = tid; e < 3072; e += 256) {
      int j = e & 7;
      int lane = (e >> 3) & 63;
      int s2 = e >> 9;
      int n = lane & 31;
      int k = 16 * s2 + ((lane >> 5) << 3) + j;
      float sc2 = bn2_g[n] * rsqrtf(bn2_v[n] + 1e-5f);
      W2_sw[e] = f2bf(w_comb[n * 96 + k] * sc2);
    }
    if (tid < 32) {
      float s1 = bn1_g[tid] * rsqrtf(bn1_v[tid] + 1e-5f);
      bias1[tid] = (b_def[tid] - bn1_m[tid]) * s1 + bn1_b[tid];
      float s2 = bn2_g[tid] * rsqrtf(bn2_v[tid] + 1e-5f);
      bias2[tid] = (b_comb[tid] - bn2_m[tid]) * s2 + bn2_b[tid];
    }
  }
}

// ---------------- K1: main fused kernel -------------------------------------
// Grid 1024 blocks, 256 thr (4 waves). bid -> (bph,cp) phase pair + spatial
// tile (4z x 4y x 8x input). Wave wv: a = wv>>1 (z-phase), ys = wv&1 (y-slab).
// Per wave: 64 output-spatial positions (2 mt x 32 m), all 96 intermediate ch.
// C^T convention throughout: MFMA col = lane&31 = spatial m.
__launch_bounds__(256, 3)
__global__ void k_main(const unsigned short* __restrict__ xT,
                       const unsigned short* __restrict__ W_sw,
                       const unsigned short* __restrict__ W2_sw,
                       const float* __restrict__ bias1f,
                       const float* __restrict__ bias2f,
                       float* __restrict__ out) {
  __shared__ unsigned short xt[17280];  // 6(z) * 5(y) * 9(x) * 64(ch)
  int tid = threadIdx.x;
  int lane = tid & 63;
  int wv = tid >> 6;
  int bid = blockIdx.x;
  int bph = (bid >> 1) & 1, cp = bid & 1;
  int tb = bid >> 2;
  int tx = tb & 3, ty = (tb >> 2) & 7, tz = tb >> 5;
  int i0 = tz * 4, j0 = ty * 4, k0 = tx * 8;

  // stage x tile (halo 1 around the accessed range; origin shifted by bph/cp)
  for (int t2 = tid; t2 < 2160; t2 += 256) {  // 270 rows * 8 ch-blocks
    int cblk = t2 & 7;
    int r = t2 >> 3;       // row = (z*5 + y)*9 + x
    int xx = r % 9;
    int zy = r / 9;
    int yy = zy % 5;
    int zz = zy / 5;
    int gz = i0 + zz - 1, gy = j0 + yy - 1 + bph, gx = k0 + xx - 1 + cp;
    uint4 v = make_uint4(0u, 0u, 0u, 0u);
    if ((unsigned)gz < 32u && (unsigned)gy < 32u && (unsigned)gx < 32u)
      v = *(const uint4*)(xT + ((((gz * 32 + gy) * 32 + gx) << 6) + (cblk << 3)));
    *(uint4*)(xt + ((r << 6) + (((cblk + r) << 3) & 63))) = v;
  }
  __syncthreads();

  int h = lane >> 5, h8 = h << 3;
  int m = lane & 31;
  int ax = m & 7, ay = (m >> 3) & 1, az = (m >> 4) & 1;
  int a = wv >> 1, ys = wv & 1;
  int p = (a << 2) | (bph << 1) | cp;
  int base = ((az + a) * 5 + (ay + 2 * ys)) * 9 + ax;

  f32x16 acc[2][3];
#pragma unroll
  for (int mt = 0; mt < 2; ++mt)
#pragma unroll
    for (int nt = 0; nt < 3; ++nt) acc[mt][nt] = (f32x16)0.f;

  const uint4* wq = (const uint4*)W_sw + p * 6144 + lane;
#pragma unroll 8
  for (int s = 0; s < 32; ++s) {
    int tap = s >> 2;
    int row0 = base + (tap >> 2) * 45 + ((tap >> 1) & 1) * 9 + (tap & 1);
    int row1 = row0 + 90;  // mt=1: z += 2
    int c0 = ((s & 3) << 4) + h8;
    int e0 = (row0 << 6) + ((c0 + (row0 << 3)) & 63);
    int e1 = (row1 << 6) + ((c0 + (row1 << 3)) & 63);
    bf16x8 a0 = bc16(*(const uint4*)(xt + e0));
    bf16x8 a1 = bc16(*(const uint4*)(xt + e1));
    const uint4* wf = wq + s * 192;
    bf16x8 bb0 = bc16(wf[0]);
    bf16x8 bb1 = bc16(wf[64]);
    bf16x8 bb2 = bc16(wf[128]);
    acc[0][0] = __builtin_amdgcn_mfma_f32_32x32x16_bf16(bb0, a0, acc[0][0], 0, 0, 0);
    acc[1][0] = __builtin_amdgcn_mfma_f32_32x32x16_bf16(bb0, a1, acc[1][0], 0, 0, 0);
    acc[0][1] = __builtin_amdgcn_mfma_f32_32x32x16_bf16(bb1, a0, acc[0][1], 0, 0, 0);
    acc[1][1] = __builtin_amdgcn_mfma_f32_32x32x16_bf16(bb1, a1, acc[1][1], 0, 0, 0);
    acc[0][2] = __builtin_amdgcn_mfma_f32_32x32x16_bf16(bb2, a0, acc[0][2], 0, 0, 0);
    acc[1][2] = __builtin_amdgcn_mfma_f32_32x32x16_bf16(bb2, a1, acc[1][2], 0, 0, 0);
  }

  // per-lane bias vectors: reg r of C^T holds channel row = (r&3)+8*(r>>2)+4h
  float b1v[16], b2v[16];
#pragma unroll
  for (int r = 0; r < 16; ++r) {
    int row = (r & 3) + ((r >> 2) << 3) + (h << 2);
    b1v[r] = bias1f[row];
    b2v[r] = bias2f[row];
  }

  const uint4* w2q = (const uint4*)W2_sw + lane;
#pragma unroll
  for (int mt = 0; mt < 2; ++mt) {
    // BN1 + ReLU + bf16 pack + cross-half exchange -> combine B-fragments.
    // word(q,c) = bf16 pair of channel rows (8q+4h+2c, +1); permlane32_swap
    // of (word(0,c),word(1,c)) and (word(2,c),word(3,c)) assembles, for each
    // lane, k-contiguous runs of 8 channels matching the mfma k-layout.
    uint4 fr[6];
#pragma unroll
    for (int nt = 0; nt < 3; ++nt) {
      unsigned ww[8];
#pragma unroll
      for (int qc = 0; qc < 8; ++qc) {
        int q = qc >> 1, c = qc & 1;
        int r0 = 4 * q + 2 * c;
        float lo = fmaxf(acc[mt][nt][r0] + b1v[r0], 0.f);
        float hi = fmaxf(acc[mt][nt][r0 + 1] + b1v[r0 + 1], 0.f);
        ww[2 * q + c] = cvtpk(lo, hi);
      }
      plswap(ww[0], ww[2]);
      plswap(ww[1], ww[3]);
      plswap(ww[4], ww[6]);
      plswap(ww[5], ww[7]);
      fr[2 * nt] = make_uint4(ww[0], ww[1], ww[2], ww[3]);
      fr[2 * nt + 1] = make_uint4(ww[4], ww[5], ww[6], ww[7]);
    }
    // fused combine GEMM (K=96), C^T: col = m, row = out-channel
    f32x16 acc2 = (f32x16)0.f;
#pragma unroll
    for (int s2 = 0; s2 < 6; ++s2)
      acc2 = __builtin_amdgcn_mfma_f32_32x32x16_bf16(bc16(w2q[s2 * 64]), bc16(fr[s2]),
                                                     acc2, 0, 0, 0);
    // BN2 + ReLU + store: lane = spatial, regs = channels (8 lines/store)
    int Z = 2 * (i0 + 2 * mt + az) + a;
    int Y = 2 * (j0 + 2 * ys + ay) + bph;
    int X = 2 * (k0 + ax) + cp;
    int sp = (Z << 12) + (Y << 6) + X;
#pragma unroll
    for (int r = 0; r < 16; ++r) {
      int ch = (r & 3) + ((r >> 2) << 3) + (h << 2);
      out[((size_t)ch << 18) + sp] = fmaxf(acc2[r] + b2v[r], 0.f);
    }
  }
}

// ---------------------------------------------------------------------------
extern "C" void kernel_launch(void* const* d_in, const int* in_sizes, int n_in,
                              void* d_out, int out_size, void* d_ws, size_t ws_size,
                              hipStream_t stream) {
  (void)in_sizes; (void)n_in; (void)out_size; (void)ws_size;
  const float* x      = (const float*)d_in[0];
  const float* w_def  = (const float*)d_in[1];
  const float* b_def  = (const float*)d_in[2];
  const float* bn1_g  = (const float*)d_in[3];
  const float* bn1_b  = (const float*)d_in[4];
  const float* bn1_m  = (const float*)d_in[5];
  const float* bn1_v  = (const float*)d_in[6];
  const float* w_comb = (const float*)d_in[7];
  const float* b_comb = (const float*)d_in[8];
  const float* bn2_g  = (const float*)d_in[9];
  const float* bn2_b  = (const float*)d_in[10];
  const float* bn2_m  = (const float*)d_in[11];
  const float* bn2_v  = (const float*)d_in[12];

  char* ws = (char*)d_ws;
  unsigned short* xT   = (unsigned short*)(ws);             // 4,194,304 B
  unsigned short* W_sw = (unsigned short*)(ws + 4194304);   //   786,432 B
  unsigned short* W2sw = (unsigned short*)(ws + 4980736);   //     6,144 B
  float* bias1 = (float*)(ws + 4986880);                    //       128 B
  float* bias2 = (float*)(ws + 4987008);                    //       128 B
  float* out = (float*)d_out;

  hipLaunchKernelGGL(k_prep, dim3(2049), dim3(256), 0, stream,
                     x, xT, w_def, bn1_g, bn1_v, W_sw,
                     w_comb, b_comb, bn2_g, bn2_b, bn2_m, bn2_v,
                     b_def, bn1_b, bn1_m, W2sw, bias1, bias2);
  hipLaunchKernelGGL(k_main, dim3(1024), dim3(256), 0, stream,
                     xT, W_sw, W2sw, bias1, bias2, out);
}

// Round 4
// 62.768 us; speedup vs baseline: 1.2634x; 1.0852x over previous
//
#include <hip/hip_runtime.h>

// ---------------------------------------------------------------------------
// UpThreeOffsetsConvShareWeights v5: v4 structure, width-16 weight staging.
//
// Same algebra (separable deform offsets -> per-phase 2x2x2-tap conv == GEMM
// M=spatial x N=96 x K=512; fused K=96 combine GEMM), C^T convention
// (mfma(W_frag, x_frag), lane = spatial), in-register cvt_pk+permlane32_swap
// relayout, full-line float2 stores (cp looped in-block).
//
// v3 (counted vmcnt) AND v4 (drain-0) both failed absmax=inf -> the bug is in
// their shared element, not the wait discipline. All new index algebra was
// re-derived and matches the proven v2 layouts; the one HW-unverified piece
// was width-12 global_load_lds (only 4B/16B are measured-good). v5: stage the
// 12288 B chunk as 12 x width-16 wave-instructions (waves 0-5, 2 each; LDS
// base wave-uniform per instruction, per-lane global addr -> linear copy,
// exactly the m97-proven pattern). Everything else identical to v4:
//  * 2-slot ring, s_waitcnt vmcnt(0) + one s_barrier per chunk; next chunk
//    issued right after the barrier, overlapping the current 24 MFMAs.
//  * bias tables in LDS (volatile reads) to cap register pressure.
//  * LDS: xt 101.25 KB + ring 24 KB + bias 0.25 KB = 128.5 KB, 1 block/CU.
// ---------------------------------------------------------------------------

typedef __bf16 bf16x8 __attribute__((ext_vector_type(8)));
typedef float f32x16 __attribute__((ext_vector_type(16)));
typedef unsigned u32x2 __attribute__((ext_vector_type(2)));

__device__ inline unsigned short f2bf(float f) {
  unsigned int u = __float_as_uint(f);
  u += 0x7FFFu + ((u >> 16) & 1u);
  return (unsigned short)(u >> 16);
}

__device__ inline bf16x8 bc16(uint4 v) { return __builtin_bit_cast(bf16x8, v); }

__device__ inline unsigned cvtpk(float lo, float hi) {
  unsigned r;
  asm("v_cvt_pk_bf16_f32 %0, %1, %2" : "=v"(r) : "v"(lo), "v"(hi));
  return r;
}

__device__ inline void plswap(unsigned& a, unsigned& b) {
  u32x2 r = __builtin_amdgcn_permlane32_swap(a, b, false, false);
  a = r.x;
  b = r.y;
}

__device__ inline void gload16(const unsigned short* g, unsigned short* l) {
  __builtin_amdgcn_global_load_lds(
      (const __attribute__((address_space(1))) unsigned int*)(const void*)g,
      (__attribute__((address_space(3))) unsigned int*)(void*)l, 16, 0, 0);
}

__device__ inline float ucoef(int abit, int k, int jbit, float alpha) {
  if (abit == 0) return (k == 0) ? (jbit ? alpha : 1.f - alpha) : (jbit ? 1.f : 0.f);
  return (k == 2) ? (jbit ? 1.f - alpha : alpha) : (jbit ? 0.f : 1.f);
}

// ---------------- K0: all preprocessing in one kernel (2049 blocks) ---------
__global__ void k_prep(const float* __restrict__ x, unsigned short* __restrict__ xT,
                       const float* __restrict__ w_def, const float* __restrict__ bn1_g,
                       const float* __restrict__ bn1_v, unsigned short* __restrict__ W_sw,
                       const float* __restrict__ w_comb, const float* __restrict__ b_comb,
                       const float* __restrict__ bn2_g, const float* __restrict__ bn2_b,
                       const float* __restrict__ bn2_m, const float* __restrict__ bn2_v,
                       const float* __restrict__ b_def, const float* __restrict__ bn1_b,
                       const float* __restrict__ bn1_m, unsigned short* __restrict__ W2_sw,
                       float* __restrict__ bias1, float* __restrict__ bias2) {
  __shared__ unsigned short t[64][65];
  int bid = blockIdx.x;
  if (bid < 512) {
    int s0 = bid * 64;
    int lane = threadIdx.x & 63;
    int grp = threadIdx.x >> 6;
#pragma unroll
    for (int c = grp; c < 64; c += 4)
      t[c][lane] = f2bf(x[c * 32768 + s0 + lane]);
    __syncthreads();
#pragma unroll
    for (int s = grp; s < 64; s += 4)
      xT[(size_t)(s0 + s) * 64 + lane] = t[lane][s];
  } else if (bid < 2048) {
    int e = (bid - 512) * 256 + threadIdx.x;  // < 393216
    int j = e & 7;
    int lane = (e >> 3) & 63;
    int idx = e >> 9;
    int nt = idx % 3;
    idx /= 3;
    int s = idx & 31;
    int p = idx >> 5;
    int o = lane & 31;
    int br = nt;
    int kk = 16 * s + ((lane >> 5) << 3) + j;
    int tap = kk >> 6, ch = kk & 63;
    int jz = (tap >> 2) & 1, jy = (tap >> 1) & 1, jx = tap & 1;
    int a = (p >> 2) & 1, b = (p >> 1) & 1, cp = p & 1;
    float alpha = (br == 0) ? 0.f : ((br == 1) ? 0.4f : 0.7f);
    const float* wb = w_def + (o * 64 + ch) * 27;
    float sum = 0.f;
    for (int kz = 0; kz < 3; ++kz) {
      float uz = ucoef(a, kz, jz, alpha);
      if (uz == 0.f) continue;
      for (int ky = 0; ky < 3; ++ky) {
        float uy = ucoef(b, ky, jy, alpha);
        if (uy == 0.f) continue;
        float uzy = uz * uy;
        for (int kx = 0; kx < 3; ++kx) {
          float ux = ucoef(cp, kx, jx, alpha);
          if (ux != 0.f) sum += wb[kz * 9 + ky * 3 + kx] * uzy * ux;
        }
      }
    }
    float s1 = bn1_g[o] * rsqrtf(bn1_v[o] + 1e-5f);
    W_sw[e] = f2bf(sum * s1);
  } else {
    int tid = threadIdx.x;
    for (int e = tid; e < 3072; e += 256) {
      int j = e & 7;
      int lane = (e >> 3) & 63;
      int s2 = e >> 9;
      int n = lane & 31;
      int k = 16 * s2 + ((lane >> 5) << 3) + j;
      float sc2 = bn2_g[n] * rsqrtf(bn2_v[n] + 1e-5f);
      W2_sw[e] = f2bf(w_comb[n * 96 + k] * sc2);
    }
    if (tid < 32) {
      float s1 = bn1_g[tid] * rsqrtf(bn1_v[tid] + 1e-5f);
      bias1[tid] = (b_def[tid] - bn1_m[tid]) * s1 + bn1_b[tid];
      float s2 = bn2_g[tid] * rsqrtf(bn2_v[tid] + 1e-5f);
      bias2[tid] = (b_comb[tid] - bn2_m[tid]) * s2 + bn2_b[tid];
    }
  }
}

// ---------------- K1: main fused kernel -------------------------------------
// Grid 256 blocks (1/CU), 512 thr (8 waves). bid -> (a,bph) + 8x8x8 tile.
// Wave wv: zs=wv>>2, ys=wv&3. Per wave M=64 (2 mt x 32 m), cp in {0,1} looped.
__launch_bounds__(512, 2)
__global__ void k_main(const unsigned short* __restrict__ xT,
                       const unsigned short* __restrict__ W_sw,
                       const unsigned short* __restrict__ W2_sw,
                       const float* __restrict__ bias1f,
                       const float* __restrict__ bias2f,
                       float* __restrict__ out) {
  __shared__ unsigned short xt[51840];       // 9*9*10 rows * 64 ch (101.25 KB)
  __shared__ unsigned short wring[2][6144];  // 2 slots * 12 KB (24 KB)
  __shared__ float blds[64];                 // bias1 | bias2 tables
  int tid = threadIdx.x;
  int lane = tid & 63;
  int wv = tid >> 6;
  int bid = blockIdx.x;
  int bph = bid & 1, a = (bid >> 1) & 1;
  int tb = bid >> 2;
  int tx = tb & 3, ty = (tb >> 2) & 3, tz = tb >> 4;
  int i0 = tz * 8, j0 = ty * 8, k0 = tx * 8;

  // ---- stage xt (halo 1; z-origin shifted by a, y-origin by bph) ----
  for (int t2 = tid; t2 < 6480; t2 += 512) {  // 810 rows * 8 ch-blocks
    int cblk = t2 & 7;
    int r = t2 >> 3;  // row = (zrel*9 + yrel)*10 + xrel
    int xrel = r % 10;
    int zy = r / 10;
    int yrel = zy % 9;
    int zrel = zy / 9;
    int gz = i0 + a - 1 + zrel, gy = j0 + bph - 1 + yrel, gx = k0 - 1 + xrel;
    uint4 v = make_uint4(0u, 0u, 0u, 0u);
    if ((unsigned)gz < 32u && (unsigned)gy < 32u && (unsigned)gx < 32u)
      v = *(const uint4*)(xT + ((((gz * 32 + gy) * 32 + gx) << 6) + (cblk << 3)));
    *(uint4*)(xt + ((r << 6) + (((cblk + r) << 3) & 63))) = v;
  }
  if (tid < 32) {
    blds[tid] = bias1f[tid];
    blds[32 + tid] = bias2f[tid];
  }

  // combine weights in registers (loaded before the big sync)
  bf16x8 b2f[6];
  const uint4* w2q = (const uint4*)W2_sw;
#pragma unroll
  for (int s2 = 0; s2 < 6; ++s2) b2f[s2] = bc16(w2q[s2 * 64 + lane]);
  __syncthreads();

  int h = lane >> 5, h8 = h << 3;
  int m = lane & 31;
  int ax = m & 7, ay = (m >> 3) & 1, az = m >> 4;
  int zs = wv >> 2, ys = wv & 3;
  int dz0 = 4 * zs + az;  // + 2*mt
  int dy = 2 * ys + ay;
  int p0 = (a << 2) | (bph << 1);

  // weight chunk stage: chunk (pn,tn) = s-steps 4tn..4tn+3 (12288 B) copied
  // linearly into wring[slot]. 12 x width-16 wave-instructions: waves 0-5
  // issue 2 each (1024 B per instruction; LDS base wave-uniform, global addr
  // per-lane +16 B). Waves 6-7 idle (drain-0 tolerates per-wave load counts).
  auto stage = [&](int pn, int tn, int slot) {
    if (wv < 6) {
      const unsigned short* g =
          W_sw + (size_t)pn * 49152 + tn * 6144 + wv * 1024 + lane * 8;
      unsigned short* l = &wring[slot][wv * 1024];
      gload16(g, l);
      gload16(g + 512, l + 512);
    }
  };

  stage(p0, 0, 0);  // prologue: chunk 0 in flight

  volatile const float* vbl = blds;  // volatile: no hoist/CSE -> no reg bloat
  f32x16 osv0, osv1;                 // cp=0 results, held across cp=1

#pragma unroll
  for (int cp = 0; cp < 2; ++cp) {
    f32x16 acc[2][3];
#pragma unroll
    for (int mt = 0; mt < 2; ++mt)
#pragma unroll
      for (int nt = 0; nt < 3; ++nt) acc[mt][nt] = (f32x16)0.f;

#pragma unroll
    for (int t = 0; t < 8; ++t) {
      int c = cp * 8 + t;  // global chunk 0..15, slot c&1
      asm volatile("s_waitcnt vmcnt(0)" ::: "memory");  // own chunk-c loads in
      __builtin_amdgcn_s_barrier();                     // all waves' parts in
      __builtin_amdgcn_sched_barrier(0);
      if (c < 15) {  // issue next chunk early; overlaps this chunk's MFMAs
        int cn = c + 1;
        stage(p0 | (cn >> 3), cn & 7, cn & 1);
      }
      __builtin_amdgcn_sched_barrier(0);
      const unsigned short* wb = &wring[c & 1][0];
      int jz = (t >> 2) & 1, jy = (t >> 1) & 1, jx = t & 1;
      int row0 = ((dz0 + jz) * 9 + (dy + jy)) * 10 + (ax + cp + jx);
      int row1 = row0 + 180;  // mt=1: z += 2
      __builtin_amdgcn_s_setprio(1);
#pragma unroll
      for (int q = 0; q < 4; ++q) {  // s = 4t+q
        int c0 = (q << 4) + h8;
        int e0 = (row0 << 6) + ((c0 + (row0 << 3)) & 63);
        int e1 = (row1 << 6) + ((c0 + (row1 << 3)) & 63);
        bf16x8 a0 = bc16(*(const uint4*)(xt + e0));
        bf16x8 a1 = bc16(*(const uint4*)(xt + e1));
        const unsigned short* wf = wb + q * 1536 + lane * 8;
        bf16x8 bb0 = bc16(*(const uint4*)(wf));
        bf16x8 bb1 = bc16(*(const uint4*)(wf + 512));
        bf16x8 bb2 = bc16(*(const uint4*)(wf + 1024));
        acc[0][0] = __builtin_amdgcn_mfma_f32_32x32x16_bf16(bb0, a0, acc[0][0], 0, 0, 0);
        acc[1][0] = __builtin_amdgcn_mfma_f32_32x32x16_bf16(bb0, a1, acc[1][0], 0, 0, 0);
        acc[0][1] = __builtin_amdgcn_mfma_f32_32x32x16_bf16(bb1, a0, acc[0][1], 0, 0, 0);
        acc[1][1] = __builtin_amdgcn_mfma_f32_32x32x16_bf16(bb1, a1, acc[1][1], 0, 0, 0);
        acc[0][2] = __builtin_amdgcn_mfma_f32_32x32x16_bf16(bb2, a0, acc[0][2], 0, 0, 0);
        acc[1][2] = __builtin_amdgcn_mfma_f32_32x32x16_bf16(bb2, a1, acc[1][2], 0, 0, 0);
      }
      __builtin_amdgcn_s_setprio(0);
      __builtin_amdgcn_sched_barrier(0);
      // NOTE: slot c&1 is only overwritten by the stage at iteration c+1,
      // which happens after the next vmcnt(0)+barrier -> no second barrier.
    }

    // ---- epilogue: BN1+ReLU, in-reg relayout, combine GEMM, BN2+ReLU ----
    // cp=0 epilogue has NO VMEM ops (keeps the ring's drain-0 overlap clean).
#pragma unroll
    for (int mt = 0; mt < 2; ++mt) {
      uint4 fr[6];
#pragma unroll
      for (int nt = 0; nt < 3; ++nt) {
        unsigned ww[8];
#pragma unroll
        for (int qc = 0; qc < 8; ++qc) {
          int q = qc >> 1, c2 = qc & 1;
          int r0 = 4 * q + 2 * c2;
          int row = (r0 & 3) + ((r0 >> 2) << 3) + (h << 2);
          float lo = fmaxf(acc[mt][nt][r0] + vbl[row], 0.f);
          float hi = fmaxf(acc[mt][nt][r0 + 1] + vbl[row + 1], 0.f);
          ww[2 * q + c2] = cvtpk(lo, hi);
        }
        plswap(ww[0], ww[2]);
        plswap(ww[1], ww[3]);
        plswap(ww[4], ww[6]);
        plswap(ww[5], ww[7]);
        fr[2 * nt] = make_uint4(ww[0], ww[1], ww[2], ww[3]);
        fr[2 * nt + 1] = make_uint4(ww[4], ww[5], ww[6], ww[7]);
      }
      f32x16 acc2 = (f32x16)0.f;
#pragma unroll
      for (int s2 = 0; s2 < 6; ++s2)
        acc2 = __builtin_amdgcn_mfma_f32_32x32x16_bf16(b2f[s2], bc16(fr[s2]), acc2, 0, 0, 0);
      if (cp == 0) {
        f32x16 ov;
#pragma unroll
        for (int r = 0; r < 16; ++r) {
          int row = (r & 3) + ((r >> 2) << 3) + (h << 2);
          ov[r] = fmaxf(acc2[r] + vbl[32 + row], 0.f);
        }
        if (mt == 0) osv0 = ov; else osv1 = ov;
      } else {
        f32x16 prev = (mt == 0) ? osv0 : osv1;
        int Z = 2 * (i0 + 4 * zs + 2 * mt + az) + a;
        int Y = 2 * (j0 + dy) + bph;
        float2* o2 = (float2*)out;
#pragma unroll
        for (int r = 0; r < 16; ++r) {
          int ch = (r & 3) + ((r >> 2) << 3) + (h << 2);
          float v1 = fmaxf(acc2[r] + vbl[32 + ch], 0.f);
          o2[((size_t)ch << 17) + ((size_t)Z << 11) + (Y << 5) + (k0 + ax)] =
              make_float2(prev[r], v1);
        }
      }
    }
  }
}

// ---------------------------------------------------------------------------
extern "C" void kernel_launch(void* const* d_in, const int* in_sizes, int n_in,
                              void* d_out, int out_size, void* d_ws, size_t ws_size,
                              hipStream_t stream) {
  (void)in_sizes; (void)n_in; (void)out_size; (void)ws_size;
  const float* x      = (const float*)d_in[0];
  const float* w_def  = (const float*)d_in[1];
  const float* b_def  = (const float*)d_in[2];
  const float* bn1_g  = (const float*)d_in[3];
  const float* bn1_b  = (const float*)d_in[4];
  const float* bn1_m  = (const float*)d_in[5];
  const float* bn1_v  = (const float*)d_in[6];
  const float* w_comb = (const float*)d_in[7];
  const float* b_comb = (const float*)d_in[8];
  const float* bn2_g  = (const float*)d_in[9];
  const float* bn2_b  = (const float*)d_in[10];
  const float* bn2_m  = (const float*)d_in[11];
  const float* bn2_v  = (const float*)d_in[12];

  char* ws = (char*)d_ws;
  unsigned short* xT   = (unsigned short*)(ws);             // 4,194,304 B
  unsigned short* W_sw = (unsigned short*)(ws + 4194304);   //   786,432 B
  unsigned short* W2sw = (unsigned short*)(ws + 4980736);   //     6,144 B
  float* bias1 = (float*)(ws + 4986880);                    //       128 B
  float* bias2 = (float*)(ws + 4987008);                    //       128 B
  float* out = (float*)d_out;

  hipLaunchKernelGGL(k_prep, dim3(2049), dim3(256), 0, stream,
                     x, xT, w_def, bn1_g, bn1_v, W_sw,
                     w_comb, b_comb, bn2_g, bn2_b, bn2_m, bn2_v,
                     b_def, bn1_b, bn1_m, W2sw, bias1, bias2);
  hipLaunchKernelGGL(k_main, dim3(256), dim3(512), 0, stream,
                     xT, W_sw, W2sw, bias1, bias2, out);
}

// Round 5
// 52.914 us; speedup vs baseline: 1.4987x; 1.1862x over previous
//
#include <hip/hip_runtime.h>

// ---------------------------------------------------------------------------
// UpThreeOffsetsConvShareWeights v6: de-synchronized 2-tap ring schedule.
//
// Same algebra (separable deform offsets -> per-phase 2x2x2-tap conv == GEMM
// M=spatial x N=96 x K=512; fused K=96 combine GEMM), C^T convention
// (mfma(W_frag, x_frag), lane = spatial), in-register cvt_pk+permlane32_swap
// relayout, full-line float2 stores (cp looped in-block). All data layouts
// byte-identical to v5 (passing).
//
// v5 post-mortem: 60 us with MFMA floor 11 us, LDS floor 13 us -> ~75% stall.
// Three different structures all hit 60 us; common cause = per-chunk lockstep
// (16x vmcnt+barrier) keeping the 2 waves/SIMD in phase so ds_read latency is
// never mutually hidden, + volatile bias reads serializing epilogues. v6:
//  * chunk = 2 taps (24 KB), 2-slot ring, 8 barriers total (halved); all 8
//    waves stage 3x gload16 (uniform); drain-0 wait has a full chunk of fly
//    time -> near-free.
//  * 8-q inner loop per chunk, no sched walls inside -> compiler pipelines
//    ds_reads across q-steps.
//  * wave desync: wave wv rotates its q-step order by 2*(wv&3) (K-slices
//    commute in acc) -> waves on a SIMD run out of phase, hiding each
//    other's LDS latency.
//  * bias reads non-volatile.
//  * LDS: xt 101.25 KB + ring 48 KB + bias 0.25 KB = 149.5 KB, 1 block/CU.
// ---------------------------------------------------------------------------

typedef __bf16 bf16x8 __attribute__((ext_vector_type(8)));
typedef float f32x16 __attribute__((ext_vector_type(16)));
typedef unsigned u32x2 __attribute__((ext_vector_type(2)));

__device__ inline unsigned short f2bf(float f) {
  unsigned int u = __float_as_uint(f);
  u += 0x7FFFu + ((u >> 16) & 1u);
  return (unsigned short)(u >> 16);
}

__device__ inline bf16x8 bc16(uint4 v) { return __builtin_bit_cast(bf16x8, v); }

__device__ inline unsigned cvtpk(float lo, float hi) {
  unsigned r;
  asm("v_cvt_pk_bf16_f32 %0, %1, %2" : "=v"(r) : "v"(lo), "v"(hi));
  return r;
}

__device__ inline void plswap(unsigned& a, unsigned& b) {
  u32x2 r = __builtin_amdgcn_permlane32_swap(a, b, false, false);
  a = r.x;
  b = r.y;
}

__device__ inline void gload16(const unsigned short* g, unsigned short* l) {
  __builtin_amdgcn_global_load_lds(
      (const __attribute__((address_space(1))) unsigned int*)(const void*)g,
      (__attribute__((address_space(3))) unsigned int*)(void*)l, 16, 0, 0);
}

__device__ inline float ucoef(int abit, int k, int jbit, float alpha) {
  if (abit == 0) return (k == 0) ? (jbit ? alpha : 1.f - alpha) : (jbit ? 1.f : 0.f);
  return (k == 2) ? (jbit ? 1.f - alpha : alpha) : (jbit ? 0.f : 1.f);
}

// ---------------- K0: all preprocessing in one kernel (2049 blocks) ---------
__global__ void k_prep(const float* __restrict__ x, unsigned short* __restrict__ xT,
                       const float* __restrict__ w_def, const float* __restrict__ bn1_g,
                       const float* __restrict__ bn1_v, unsigned short* __restrict__ W_sw,
                       const float* __restrict__ w_comb, const float* __restrict__ b_comb,
                       const float* __restrict__ bn2_g, const float* __restrict__ bn2_b,
                       const float* __restrict__ bn2_m, const float* __restrict__ bn2_v,
                       const float* __restrict__ b_def, const float* __restrict__ bn1_b,
                       const float* __restrict__ bn1_m, unsigned short* __restrict__ W2_sw,
                       float* __restrict__ bias1, float* __restrict__ bias2) {
  __shared__ unsigned short t[64][65];
  int bid = blockIdx.x;
  if (bid < 512) {
    int s0 = bid * 64;
    int lane = threadIdx.x & 63;
    int grp = threadIdx.x >> 6;
#pragma unroll
    for (int c = grp; c < 64; c += 4)
      t[c][lane] = f2bf(x[c * 32768 + s0 + lane]);
    __syncthreads();
#pragma unroll
    for (int s = grp; s < 64; s += 4)
      xT[(size_t)(s0 + s) * 64 + lane] = t[lane][s];
  } else if (bid < 2048) {
    int e = (bid - 512) * 256 + threadIdx.x;  // < 393216
    int j = e & 7;
    int lane = (e >> 3) & 63;
    int idx = e >> 9;
    int nt = idx % 3;
    idx /= 3;
    int s = idx & 31;
    int p = idx >> 5;
    int o = lane & 31;
    int br = nt;
    int kk = 16 * s + ((lane >> 5) << 3) + j;
    int tap = kk >> 6, ch = kk & 63;
    int jz = (tap >> 2) & 1, jy = (tap >> 1) & 1, jx = tap & 1;
    int a = (p >> 2) & 1, b = (p >> 1) & 1, cp = p & 1;
    float alpha = (br == 0) ? 0.f : ((br == 1) ? 0.4f : 0.7f);
    const float* wb = w_def + (o * 64 + ch) * 27;
    float sum = 0.f;
    for (int kz = 0; kz < 3; ++kz) {
      float uz = ucoef(a, kz, jz, alpha);
      if (uz == 0.f) continue;
      for (int ky = 0; ky < 3; ++ky) {
        float uy = ucoef(b, ky, jy, alpha);
        if (uy == 0.f) continue;
        float uzy = uz * uy;
        for (int kx = 0; kx < 3; ++kx) {
          float ux = ucoef(cp, kx, jx, alpha);
          if (ux != 0.f) sum += wb[kz * 9 + ky * 3 + kx] * uzy * ux;
        }
      }
    }
    float s1 = bn1_g[o] * rsqrtf(bn1_v[o] + 1e-5f);
    W_sw[e] = f2bf(sum * s1);
  } else {
    int tid = threadIdx.x;
    for (int e = tid; e < 3072; e += 256) {
      int j = e & 7;
      int lane = (e >> 3) & 63;
      int s2 = e >> 9;
      int n = lane & 31;
      int k = 16 * s2 + ((lane >> 5) << 3) + j;
      float sc2 = bn2_g[n] * rsqrtf(bn2_v[n] + 1e-5f);
      W2_sw[e] = f2bf(w_comb[n * 96 + k] * sc2);
    }
    if (tid < 32) {
      float s1 = bn1_g[tid] * rsqrtf(bn1_v[tid] + 1e-5f);
      bias1[tid] = (b_def[tid] - bn1_m[tid]) * s1 + bn1_b[tid];
      float s2 = bn2_g[tid] * rsqrtf(bn2_v[tid] + 1e-5f);
      bias2[tid] = (b_comb[tid] - bn2_m[tid]) * s2 + bn2_b[tid];
    }
  }
}

// ---------------- K1: main fused kernel -------------------------------------
// Grid 256 blocks (1/CU), 512 thr (8 waves). bid -> (a,bph) + 8x8x8 tile.
// Wave wv: zs=wv>>2, ys=wv&3. Per wave M=64 (2 mt x 32 m), cp = chunk>>2.
__launch_bounds__(512, 2)
__global__ void k_main(const unsigned short* __restrict__ xT,
                       const unsigned short* __restrict__ W_sw,
                       const unsigned short* __restrict__ W2_sw,
                       const float* __restrict__ bias1f,
                       const float* __restrict__ bias2f,
                       float* __restrict__ out) {
  __shared__ unsigned short xt[51840];        // 9*9*10 rows * 64 ch (101.25 KB)
  __shared__ unsigned short wring[2][12288];  // 2 slots * 24 KB = 2 taps each
  __shared__ float blds[64];                  // bias1 | bias2 tables
  int tid = threadIdx.x;
  int lane = tid & 63;
  int wv = tid >> 6;
  int bid = blockIdx.x;
  int bph = bid & 1, a = (bid >> 1) & 1;
  int tb = bid >> 2;
  int tx = tb & 3, ty = (tb >> 2) & 3, tz = tb >> 4;
  int i0 = tz * 8, j0 = ty * 8, k0 = tx * 8;

  // ---- stage xt (halo 1; z-origin shifted by a, y-origin by bph) ----
  for (int t2 = tid; t2 < 6480; t2 += 512) {  // 810 rows * 8 ch-blocks
    int cblk = t2 & 7;
    int r = t2 >> 3;  // row = (zrel*9 + yrel)*10 + xrel
    int xrel = r % 10;
    int zy = r / 10;
    int yrel = zy % 9;
    int zrel = zy / 9;
    int gz = i0 + a - 1 + zrel, gy = j0 + bph - 1 + yrel, gx = k0 - 1 + xrel;
    uint4 v = make_uint4(0u, 0u, 0u, 0u);
    if ((unsigned)gz < 32u && (unsigned)gy < 32u && (unsigned)gx < 32u)
      v = *(const uint4*)(xT + ((((gz * 32 + gy) * 32 + gx) << 6) + (cblk << 3)));
    *(uint4*)(xt + ((r << 6) + (((cblk + r) << 3) & 63))) = v;
  }
  if (tid < 32) {
    blds[tid] = bias1f[tid];
    blds[32 + tid] = bias2f[tid];
  }

  // combine weights in registers (loaded before the big sync)
  bf16x8 b2f[6];
  const uint4* w2q = (const uint4*)W2_sw;
#pragma unroll
  for (int s2 = 0; s2 < 6; ++s2) b2f[s2] = bc16(w2q[s2 * 64 + lane]);
  __syncthreads();

  int h = lane >> 5, h8 = h << 3;
  int m = lane & 31;
  int ax = m & 7, ay = (m >> 3) & 1, az = m >> 4;
  int zs = wv >> 2, ys = wv & 3;
  int dz0 = 4 * zs + az;  // + 2*mt
  int dy = 2 * ys + ay;
  int p0 = (a << 2) | (bph << 1);

  // chunk cc (0..7) = phase p0|(cc>>2), taps {2*(cc&3), 2*(cc&3)+1} (24576 B).
  // All 8 waves stage 3072 B each: 3 x width-16 wave-instructions.
  auto stage = [&](int cc) {
    int pn = p0 | (cc >> 2);
    const unsigned short* g =
        W_sw + (size_t)pn * 49152 + (cc & 3) * 12288 + wv * 1536 + lane * 8;
    unsigned short* l = &wring[cc & 1][wv * 1536];
    gload16(g, l);
    gload16(g + 512, l + 512);
    gload16(g + 1024, l + 1024);
  };

  stage(0);  // prologue: chunk 0 in flight

  f32x16 osv0, osv1;  // cp=0 results, held across cp=1
  f32x16 acc[2][3];
#pragma unroll
  for (int mt = 0; mt < 2; ++mt)
#pragma unroll
    for (int nt = 0; nt < 3; ++nt) acc[mt][nt] = (f32x16)0.f;

  int qr = (wv & 3) * 2;  // per-wave K-slice rotation (desync; acc commutes)

  for (int cc = 0; cc < 8; ++cc) {
    asm volatile("s_waitcnt vmcnt(0)" ::: "memory");  // own chunk-cc loads in
    __builtin_amdgcn_s_barrier();                     // all waves' parts in
    __builtin_amdgcn_sched_barrier(0);
    if (cc < 7) stage(cc + 1);  // next chunk flies during this chunk's work
    __builtin_amdgcn_sched_barrier(0);
    int cp = cc >> 2;
    int tb2 = (cc & 3) * 2;
    const unsigned short* wfb = &wring[cc & 1][lane * 8];
#pragma unroll
    for (int i = 0; i < 8; ++i) {  // 8 q-steps (2 taps x 4), rotated per wave
      int q2 = (i + qr) & 7;
      int tl = q2 >> 2, q = q2 & 3;
      int t8 = tb2 + tl;
      int jz = (t8 >> 2) & 1, jy = (t8 >> 1) & 1, jx = t8 & 1;
      int row0 = ((dz0 + jz) * 9 + (dy + jy)) * 10 + (ax + cp + jx);
      int row1 = row0 + 180;  // mt=1: z += 2
      int c0 = (q << 4) + h8;
      int e0 = (row0 << 6) + ((c0 + (row0 << 3)) & 63);
      int e1 = (row1 << 6) + ((c0 + (row1 << 3)) & 63);
      bf16x8 a0 = bc16(*(const uint4*)(xt + e0));
      bf16x8 a1 = bc16(*(const uint4*)(xt + e1));
      const unsigned short* wf = wfb + tl * 6144 + q * 1536;
      bf16x8 bb0 = bc16(*(const uint4*)(wf));
      bf16x8 bb1 = bc16(*(const uint4*)(wf + 512));
      bf16x8 bb2 = bc16(*(const uint4*)(wf + 1024));
      __builtin_amdgcn_s_setprio(1);
      acc[0][0] = __builtin_amdgcn_mfma_f32_32x32x16_bf16(bb0, a0, acc[0][0], 0, 0, 0);
      acc[1][0] = __builtin_amdgcn_mfma_f32_32x32x16_bf16(bb0, a1, acc[1][0], 0, 0, 0);
      acc[0][1] = __builtin_amdgcn_mfma_f32_32x32x16_bf16(bb1, a0, acc[0][1], 0, 0, 0);
      acc[1][1] = __builtin_amdgcn_mfma_f32_32x32x16_bf16(bb1, a1, acc[1][1], 0, 0, 0);
      acc[0][2] = __builtin_amdgcn_mfma_f32_32x32x16_bf16(bb2, a0, acc[0][2], 0, 0, 0);
      acc[1][2] = __builtin_amdgcn_mfma_f32_32x32x16_bf16(bb2, a1, acc[1][2], 0, 0, 0);
      __builtin_amdgcn_s_setprio(0);
    }

    if (cc == 3) {
      // ---- cp=0 epilogue: BN1+ReLU, in-reg relayout, combine, BN2+ReLU ----
      // (no VMEM, no LDS writes; bias reads are plain LDS broadcasts)
#pragma unroll
      for (int mt = 0; mt < 2; ++mt) {
        uint4 fr[6];
#pragma unroll
        for (int nt = 0; nt < 3; ++nt) {
          unsigned ww[8];
#pragma unroll
          for (int qc = 0; qc < 8; ++qc) {
            int q = qc >> 1, c2 = qc & 1;
            int r0 = 4 * q + 2 * c2;
            int row = (r0 & 3) + ((r0 >> 2) << 3) + (h << 2);
            float lo = fmaxf(acc[mt][nt][r0] + blds[row], 0.f);
            float hi = fmaxf(acc[mt][nt][r0 + 1] + blds[row + 1], 0.f);
            ww[2 * q + c2] = cvtpk(lo, hi);
          }
          plswap(ww[0], ww[2]);
          plswap(ww[1], ww[3]);
          plswap(ww[4], ww[6]);
          plswap(ww[5], ww[7]);
          fr[2 * nt] = make_uint4(ww[0], ww[1], ww[2], ww[3]);
          fr[2 * nt + 1] = make_uint4(ww[4], ww[5], ww[6], ww[7]);
        }
        f32x16 acc2 = (f32x16)0.f;
#pragma unroll
        for (int s2 = 0; s2 < 6; ++s2)
          acc2 = __builtin_amdgcn_mfma_f32_32x32x16_bf16(b2f[s2], bc16(fr[s2]), acc2, 0, 0, 0);
        f32x16 ov;
#pragma unroll
        for (int r = 0; r < 16; ++r) {
          int row = (r & 3) + ((r >> 2) << 3) + (h << 2);
          ov[r] = fmaxf(acc2[r] + blds[32 + row], 0.f);
        }
        if (mt == 0) osv0 = ov; else osv1 = ov;
#pragma unroll
        for (int nt = 0; nt < 3; ++nt) acc[mt][nt] = (f32x16)0.f;
      }
    }
  }

  // ---- cp=1 epilogue: same pipeline + full-line float2 stores ----
#pragma unroll
  for (int mt = 0; mt < 2; ++mt) {
    uint4 fr[6];
#pragma unroll
    for (int nt = 0; nt < 3; ++nt) {
      unsigned ww[8];
#pragma unroll
      for (int qc = 0; qc < 8; ++qc) {
        int q = qc >> 1, c2 = qc & 1;
        int r0 = 4 * q + 2 * c2;
        int row = (r0 & 3) + ((r0 >> 2) << 3) + (h << 2);
        float lo = fmaxf(acc[mt][nt][r0] + blds[row], 0.f);
        float hi = fmaxf(acc[mt][nt][r0 + 1] + blds[row + 1], 0.f);
        ww[2 * q + c2] = cvtpk(lo, hi);
      }
      plswap(ww[0], ww[2]);
      plswap(ww[1], ww[3]);
      plswap(ww[4], ww[6]);
      plswap(ww[5], ww[7]);
      fr[2 * nt] = make_uint4(ww[0], ww[1], ww[2], ww[3]);
      fr[2 * nt + 1] = make_uint4(ww[4], ww[5], ww[6], ww[7]);
    }
    f32x16 acc2 = (f32x16)0.f;
#pragma unroll
    for (int s2 = 0; s2 < 6; ++s2)
      acc2 = __builtin_amdgcn_mfma_f32_32x32x16_bf16(b2f[s2], bc16(fr[s2]), acc2, 0, 0, 0);
    f32x16 prev = (mt == 0) ? osv0 : osv1;
    int Z = 2 * (i0 + 4 * zs + 2 * mt + az) + a;
    int Y = 2 * (j0 + dy) + bph;
    float2* o2 = (float2*)out;
#pragma unroll
    for (int r = 0; r < 16; ++r) {
      int ch = (r & 3) + ((r >> 2) << 3) + (h << 2);
      float v1 = fmaxf(acc2[r] + blds[32 + ch], 0.f);
      o2[((size_t)ch << 17) + ((size_t)Z << 11) + (Y << 5) + (k0 + ax)] =
          make_float2(prev[r], v1);
    }
  }
}

// ---------------------------------------------------------------------------
extern "C" void kernel_launch(void* const* d_in, const int* in_sizes, int n_in,
                              void* d_out, int out_size, void* d_ws, size_t ws_size,
                              hipStream_t stream) {
  (void)in_sizes; (void)n_in; (void)out_size; (void)ws_size;
  const float* x      = (const float*)d_in[0];
  const float* w_def  = (const float*)d_in[1];
  const float* b_def  = (const float*)d_in[2];
  const float* bn1_g  = (const float*)d_in[3];
  const float* bn1_b  = (const float*)d_in[4];
  const float* bn1_m  = (const float*)d_in[5];
  const float* bn1_v  = (const float*)d_in[6];
  const float* w_comb = (const float*)d_in[7];
  const float* b_comb = (const float*)d_in[8];
  const float* bn2_g  = (const float*)d_in[9];
  const float* bn2_b  = (const float*)d_in[10];
  const float* bn2_m  = (const float*)d_in[11];
  const float* bn2_v  = (const float*)d_in[12];

  char* ws = (char*)d_ws;
  unsigned short* xT   = (unsigned short*)(ws);             // 4,194,304 B
  unsigned short* W_sw = (unsigned short*)(ws + 4194304);   //   786,432 B
  unsigned short* W2sw = (unsigned short*)(ws + 4980736);   //     6,144 B
  float* bias1 = (float*)(ws + 4986880);                    //       128 B
  float* bias2 = (float*)(ws + 4987008);                    //       128 B
  float* out = (float*)d_out;

  hipLaunchKernelGGL(k_prep, dim3(2049), dim3(256), 0, stream,
                     x, xT, w_def, bn1_g, bn1_v, W_sw,
                     w_comb, b_comb, bn2_g, bn2_b, bn2_m, bn2_v,
                     b_def, bn1_b, bn1_m, W2sw, bias1, bias2);
  hipLaunchKernelGGL(k_main, dim3(256), dim3(512), 0, stream,
                     xT, W_sw, W2sw, bias1, bias2, out);
}